// Round 1
// baseline (499.495 us; speedup 1.0000x reference)
//
#include <hip/hip_runtime.h>

#define HD 2048
#define HH (HD*HD)

// DT=0.001, DX=0.02  ->  DT^2/DX^2 = 0.0025, DT/DX = 0.05
__device__ __forceinline__ float coef_of(float rs) { return rs * rs * 0.0025f; }

// ---------------- Kernel A: y = conv3x3([xtt, xt, ref_speed], W) + b --------
__global__ __launch_bounds__(256) void conv_y_kernel(
    const float* __restrict__ batch,
    const float* __restrict__ rs,
    const float* __restrict__ conv_v,
    const float* __restrict__ conv_g,
    const float* __restrict__ conv_b,
    const int* __restrict__ p_bsize,
    const int* __restrict__ p_flag,
    const int* __restrict__ p_flagnum,
    float* __restrict__ y)
{
    int idx = blockIdx.x * blockDim.x + threadIdx.x;
    if (idx >= HH) return;
    int i = idx >> 11;          // row
    int j = idx & (HD - 1);     // col

    int base = ((p_flag[0] - 1) * p_bsize[0] + (p_flagnum[0] - 1)) * HH;
    const float* __restrict__ xtt = batch + base;
    const float* __restrict__ xt  = batch + base + HH;

    // normalized weights (27 values, broadcast via caches)
    float ss = 0.f;
    float w[27];
    #pragma unroll
    for (int k = 0; k < 27; ++k) { w[k] = conv_v[k]; ss += w[k] * w[k]; }
    float scale = conv_g[0] / sqrtf(ss);

    float acc = conv_b[0];
    #pragma unroll
    for (int kh = 0; kh < 3; ++kh) {
        int ii = i + kh - 1;
        if (ii < 0 || ii >= HD) continue;
        #pragma unroll
        for (int kw = 0; kw < 3; ++kw) {
            int jj = j + kw - 1;
            if (jj < 0 || jj >= HD) continue;
            int o = ii * HD + jj;
            acc += scale * (w[kh * 3 + kw]      * xtt[o]
                          + w[9 + kh * 3 + kw]  * xt[o]
                          + w[18 + kh * 3 + kw] * rs[o]);
        }
    }
    y[idx] = acc;
}

// ---------------- Kernel B: all 7 output planes ----------------------------
__global__ __launch_bounds__(256) void main_kernel(
    const float* __restrict__ batch,
    const float* __restrict__ rs,
    const float* __restrict__ x_tt_in,
    const float* __restrict__ x_t_in,
    const float* __restrict__ y,
    const int* __restrict__ p_bsize,
    const int* __restrict__ p_flag,
    const int* __restrict__ p_flagnum,
    float* __restrict__ out)
{
    int idx = blockIdx.x * blockDim.x + threadIdx.x;
    if (idx >= HH) return;
    int i = idx >> 11;
    int j = idx & (HD - 1);

    int base = ((p_flag[0] - 1) * p_bsize[0] + (p_flagnum[0] - 1)) * HH;
    const float* __restrict__ xtt = batch + base;
    const float* __restrict__ xt  = batch + base + HH;

    float a_tt = x_tt_in[idx];
    float a_t  = x_t_in[idx];
    out[idx]            = a_tt;   // plane 0
    out[HH + idx]       = a_t;    // plane 1
    out[3 * HH + idx]   = a_tt;   // plane 3
    out[4 * HH + idx]   = a_t;    // plane 4

    float xc = xt[idx];
    float xo = xtt[idx];
    float rc = rs[idx];
    float yc = y[idx];

    bool interior = (i > 0) & (i < HD - 1) & (j > 0) & (j < HD - 1);

    float xt4 = 0.f;
    float ypre;
    if (interior) {
        float coef = coef_of(rc);
        float lapx = xt[idx - HD] + xt[idx + HD] + xt[idx - 1] + xt[idx + 1] - 4.f * xc;
        xt4 = 2.f * xc - xo + lapx * coef;
        float lapy = y[idx - HD] + y[idx + HD] + y[idx - 1] + y[idx + 1] - 4.f * yc;
        ypre = 2.f * xc - xo + lapy * coef;
    } else {
        ypre = yc;
    }
    out[6 * HH + idx] = xt4;   // plane 6 (x_t4)
    out[5 * HH + idx] = ypre;  // plane 5 (x7_pre)

    // Boundary-condition precedence chain, matching reference overwrite order:
    // row0=0 -> left col -> anti-diagonal -> right col -> rowH-1=0
    float v = ypre;
    if (i == 0) v = 0.f;
    if (j == 0) {
        float x1 = xt[i * HD + 1];
        v = xc - 0.05f * rc * (xc - x1);
    }
    if (i >= 1 && i <= HD - 2 && j == HD - i) {
        v = xt[(i - 1) * HD + (j - 1)];
    }
    if (j == HD - 1) {
        float x1 = xt[i * HD + HD - 2];
        v = xc - 0.05f * rc * (xc - x1);
    }
    if (i == HD - 1) v = 0.f;
    out[2 * HH + idx] = v;     // plane 2 (x7)
}

// ---------------- Kernel C: 256-point observation scatter ------------------
__global__ __launch_bounds__(256) void scatter_kernel(
    const float* __restrict__ ref_sol,
    const int* __restrict__ loc_x,
    const int* __restrict__ loc_y,
    const int* __restrict__ p_bsize,
    const int* __restrict__ p_id,
    const int* __restrict__ p_flagnum,
    float* __restrict__ out)
{
    int k = blockIdx.x * blockDim.x + threadIdx.x;
    if (k >= 256) return;
    int lx = loc_x[k];
    if (lx == -1) return;
    int ly = loc_y[k];
    int off = (p_id[0] * p_bsize[0] + (p_flagnum[0] - 1) + 2) * HH;
    out[2 * HH + lx * HD + ly] = ref_sol[off + lx * HD + ly];
}

extern "C" void kernel_launch(void* const* d_in, const int* in_sizes, int n_in,
                              void* d_out, int out_size, void* d_ws, size_t ws_size,
                              hipStream_t stream) {
    const float* ref_speed = (const float*)d_in[0];
    const float* batch     = (const float*)d_in[1];
    const float* x_tt      = (const float*)d_in[2];
    const float* x_t       = (const float*)d_in[3];
    const float* ref_sol   = (const float*)d_in[4];
    const float* conv_v    = (const float*)d_in[5];
    const float* conv_g    = (const float*)d_in[6];
    const float* conv_b    = (const float*)d_in[7];
    const int*   loc_x     = (const int*)d_in[8];
    const int*   loc_y     = (const int*)d_in[9];
    const int*   bsize     = (const int*)d_in[10];
    const int*   id        = (const int*)d_in[11];
    const int*   flag      = (const int*)d_in[12];
    const int*   flag_num  = (const int*)d_in[13];

    float* out = (float*)d_out;
    float* y   = (float*)d_ws;   // HH floats of scratch

    dim3 block(256);
    dim3 grid((HH + 255) / 256);

    conv_y_kernel<<<grid, block, 0, stream>>>(batch, ref_speed, conv_v, conv_g, conv_b,
                                              bsize, flag, flag_num, y);
    main_kernel<<<grid, block, 0, stream>>>(batch, ref_speed, x_tt, x_t, y,
                                            bsize, flag, flag_num, out);
    scatter_kernel<<<1, 256, 0, stream>>>(ref_sol, loc_x, loc_y, bsize, id, flag_num, out);
}

// Round 2
// 492.453 us; speedup vs baseline: 1.0143x; 1.0143x over previous
//
#include <hip/hip_runtime.h>

#define HD   2048
#define HHW  (HD*HD)
#define TX   64          // output tile cols
#define TY   32          // output tile rows
#define XSTR 68          // LDS row stride (floats); 68 % 32 = 4-bank skew
#define XROWS 36         // xt halo rows  (TY+4)
#define YROWS 34         // y  halo rows  (TY+2)
#define YCOLS 66         // y  halo cols  (TX+2)

// DT=0.001, DX=0.02 -> DT^2/DX^2 = 0.0025, DT/DX = 0.05

__global__ __launch_bounds__(256) void fused_kernel(
    const float* __restrict__ batch,
    const float* __restrict__ rs,
    const float* __restrict__ x_tt_in,
    const float* __restrict__ x_t_in,
    const float* __restrict__ conv_v,
    const float* __restrict__ conv_g,
    const float* __restrict__ conv_b,
    const int* __restrict__ p_bsize,
    const int* __restrict__ p_flag,
    const int* __restrict__ p_flagnum,
    float* __restrict__ out)
{
    __shared__ float xts[XROWS * XSTR];  // xt tile, origin (gi0-2, gj0-2)
    __shared__ float ys [YROWS * XSTR];  // y  tile, origin (gi0-1, gj0-1)

    const int tid = threadIdx.x;
    const int gi0 = blockIdx.y * TY;
    const int gj0 = blockIdx.x * TX;

    const int base = ((p_flag[0] - 1) * p_bsize[0] + (p_flagnum[0] - 1)) * HHW;
    const float* __restrict__ xtt = batch + base;
    const float* __restrict__ xt  = batch + base + HHW;

    // ---- weights (uniform address -> scalar loads), normalize once ----
    float w[27];
    float ss = 0.f;
    #pragma unroll
    for (int k = 0; k < 27; ++k) { w[k] = conv_v[k]; ss += w[k] * w[k]; }
    const float scale = conv_g[0] / sqrtf(ss);
    const float bias  = conv_b[0];

    // ---- stage 0: xt halo region -> LDS (zero outside domain) ----
    for (int p = tid; p < XROWS * XSTR; p += 256) {
        int li = p / XSTR;
        int lj = p - li * XSTR;
        int gi = gi0 - 2 + li;
        int gj = gj0 - 2 + lj;
        float v = 0.f;
        if ((unsigned)gi < HD && (unsigned)gj < HD) v = xt[gi * HD + gj];
        xts[p] = v;
    }
    __syncthreads();

    // ---- stage 1: y = conv3x3([xtt, xt, rs]) over the (TY+2)x(TX+2) halo ----
    for (int p = tid; p < YROWS * YCOLS; p += 256) {
        int li = p / YCOLS;
        int lj = p - li * YCOLS;
        int gi = gi0 - 1 + li;
        int gj = gj0 - 1 + lj;
        if ((unsigned)gi >= HD || (unsigned)gj >= HD) continue;  // never read back
        float acc = 0.f;
        #pragma unroll
        for (int kh = 0; kh < 3; ++kh) {
            int ii = gi + kh - 1;
            bool rok = (unsigned)ii < HD;
            const float* rowt = xtt + ii * HD;
            const float* rowr = rs  + ii * HD;
            #pragma unroll
            for (int kw = 0; kw < 3; ++kw) {
                int jj = gj + kw - 1;
                bool ok = rok && ((unsigned)jj < HD);
                float t0 = ok ? rowt[jj] : 0.f;                      // xtt tap
                float t1 = xts[(li + kh) * XSTR + lj + kw];          // xt tap (LDS, zero-padded)
                float t2 = ok ? rowr[jj] : 0.f;                      // rs tap
                acc += w[kh * 3 + kw]      * t0
                     + w[9 + kh * 3 + kw]  * t1
                     + w[18 + kh * 3 + kw] * t2;
            }
        }
        ys[li * XSTR + lj] = bias + scale * acc;
    }
    __syncthreads();

    // ---- stage 2: all 7 output planes; wave = one 64-wide row (coalesced) ----
    const int c  = tid & 63;
    const int rg = tid >> 6;
    for (int k = 0; k < 8; ++k) {
        int row = rg * 8 + k;
        int gi  = gi0 + row;
        int gj  = gj0 + c;
        int idx = gi * HD + gj;

        float a_tt = x_tt_in[idx];
        float a_t  = x_t_in[idx];
        float xc = xts[(row + 2) * XSTR + c + 2];
        float xo = xtt[idx];
        float rc = rs[idx];
        float yc = ys[(row + 1) * XSTR + c + 1];

        bool interior = (gi > 0) & (gi < HD - 1) & (gj > 0) & (gj < HD - 1);
        float xt4 = 0.f, ypre;
        if (interior) {
            float coef = rc * rc * 0.0025f;
            float lapx = xts[(row + 1) * XSTR + c + 2] + xts[(row + 3) * XSTR + c + 2]
                       + xts[(row + 2) * XSTR + c + 1] + xts[(row + 2) * XSTR + c + 3] - 4.f * xc;
            xt4 = 2.f * xc - xo + lapx * coef;
            float lapy = ys[row * XSTR + c + 1] + ys[(row + 2) * XSTR + c + 1]
                       + ys[(row + 1) * XSTR + c] + ys[(row + 1) * XSTR + c + 2] - 4.f * yc;
            ypre = 2.f * xc - xo + lapy * coef;
        } else {
            ypre = yc;
        }

        // BC precedence chain (reference overwrite order):
        // row0=0 -> left col -> anti-diagonal -> right col -> rowH-1=0
        float v = ypre;
        if (gi == 0) v = 0.f;
        if (gj == 0)      v = xc - 0.05f * rc * (xc - xts[(row + 2) * XSTR + 3]);
        if (gi >= 1 && gi <= HD - 2 && gj == HD - gi)
                          v = xts[(row + 1) * XSTR + c + 1];   // xt[gi-1][gj-1]
        if (gj == HD - 1) v = xc - 0.05f * rc * (xc - xts[(row + 2) * XSTR + c + 1]);
        if (gi == HD - 1) v = 0.f;

        out[idx]            = a_tt;  // plane 0: x_tt
        out[HHW + idx]      = a_t;   // plane 1: x_t
        out[2 * HHW + idx]  = v;     // plane 2: x7
        out[3 * HHW + idx]  = a_tt;  // plane 3: x_tt
        out[4 * HHW + idx]  = a_t;   // plane 4: x_t
        out[5 * HHW + idx]  = ypre;  // plane 5: x7_pre
        out[6 * HHW + idx]  = xt4;   // plane 6: x_t4
    }
}

// ---------------- observation scatter (runs last => wins over BCs) ---------
__global__ __launch_bounds__(256) void scatter_kernel(
    const float* __restrict__ ref_sol,
    const int* __restrict__ loc_x,
    const int* __restrict__ loc_y,
    const int* __restrict__ p_bsize,
    const int* __restrict__ p_id,
    const int* __restrict__ p_flagnum,
    float* __restrict__ out)
{
    int k = blockIdx.x * blockDim.x + threadIdx.x;
    if (k >= 256) return;
    int lx = loc_x[k];
    if (lx == -1) return;
    int ly = loc_y[k];
    int off = (p_id[0] * p_bsize[0] + (p_flagnum[0] - 1) + 2) * HHW;
    out[2 * HHW + lx * HD + ly] = ref_sol[off + lx * HD + ly];
}

extern "C" void kernel_launch(void* const* d_in, const int* in_sizes, int n_in,
                              void* d_out, int out_size, void* d_ws, size_t ws_size,
                              hipStream_t stream) {
    const float* ref_speed = (const float*)d_in[0];
    const float* batch     = (const float*)d_in[1];
    const float* x_tt      = (const float*)d_in[2];
    const float* x_t       = (const float*)d_in[3];
    const float* ref_sol   = (const float*)d_in[4];
    const float* conv_v    = (const float*)d_in[5];
    const float* conv_g    = (const float*)d_in[6];
    const float* conv_b    = (const float*)d_in[7];
    const int*   loc_x     = (const int*)d_in[8];
    const int*   loc_y     = (const int*)d_in[9];
    const int*   bsize     = (const int*)d_in[10];
    const int*   id        = (const int*)d_in[11];
    const int*   flag      = (const int*)d_in[12];
    const int*   flag_num  = (const int*)d_in[13];

    float* out = (float*)d_out;

    dim3 block(256);
    dim3 grid(HD / TX, HD / TY);   // 32 x 64 blocks

    fused_kernel<<<grid, block, 0, stream>>>(batch, ref_speed, x_tt, x_t,
                                             conv_v, conv_g, conv_b,
                                             bsize, flag, flag_num, out);
    scatter_kernel<<<1, 256, 0, stream>>>(ref_sol, loc_x, loc_y, bsize, id, flag_num, out);
}